// Round 5
// baseline (211.497 us; speedup 1.0000x reference)
//
#include <hip/hip_runtime.h>
#include <hip/hip_bf16.h>

#define D 64
#define K 400
#define KT 25            // K/16 code tiles
#define MA 4             // A-row-tiles per wave (64 rows)

typedef _Float16 f16x8 __attribute__((ext_vector_type(8)));
typedef float f32x4 __attribute__((ext_vector_type(4)));

// ws layout: [KT][4][64] f16x8 B-fragments (102,400 B) then 400 floats -||e||^2.
#define WS_FRAG_HALVES (KT * 4 * 64 * 8)
#define WS_NEED (WS_FRAG_HALVES * 2 + K * 4)

// ---- prologue: build fragment-ordered hi/lo codebook + negated norms in ws ----
// argmin_k ||e_k||^2 - 2 x.e_k via f16 hi/lo split (22-bit effective):
//   2e = eh + 2^-11 el  (el stored pre-scaled by 2^11, stays f16-normal)
__global__ __launch_bounds__(256) void vq_prep(const float* __restrict__ emb,
                                               _Float16* __restrict__ wfrag,
                                               float* __restrict__ wnnorm) {
  const int t = blockIdx.x;          // 25 blocks, one tile each
  const int tid = threadIdx.x;       // 256: f = tid>>6, lane = tid&63
  const int f = tid >> 6;
  const int l = tid & 63;
  const int code = t * 16 + (l & 15);
  const int kb = ((l >> 4) << 3) + ((f >> 1) << 5);
  const float* ep = emb + code * D + kb;
  float v[8];
  *(float4*)&v[0] = *(const float4*)ep;
  *(float4*)&v[4] = *(const float4*)(ep + 4);
  _Float16 h[8];
  if ((f & 1) == 0) {
#pragma unroll
    for (int j = 0; j < 8; ++j) h[j] = (_Float16)(2.0f * v[j]);
  } else {
#pragma unroll
    for (int j = 0; j < 8; ++j) {
      float s = 2.0f * v[j];
      _Float16 hh = (_Float16)s;
      float r = s - (float)hh;
      h[j] = (_Float16)(r * 2048.0f);
    }
  }
  *(f16x8*)(wfrag + (size_t)((t * 4 + f) * 64 + l) * 8) = *(f16x8*)&h[0];
  if (tid < 16) {
    const float* np = emb + (t * 16 + tid) * D;
    float s = 0.f;
#pragma unroll
    for (int d = 0; d < D; ++d) s = fmaf(np[d], np[d], s);
    wnnorm[t * 16 + tid] = -s;
  }
}

// ---- main: no LDS, no barriers; B-frags from L1/L2-hot ws ----
__global__ __launch_bounds__(256, 4) void vq_main(
    const float* __restrict__ x,
    const _Float16* __restrict__ wfrag,
    const float* __restrict__ wnnorm,
    const float* __restrict__ emb,
    float* __restrict__ out,
    int nrows) {
  const int lane = threadIdx.x & 63;
  const int wid = threadIdx.x >> 6;
  const int gw = blockIdx.x * 4 + wid;
  const int row0 = gw << 6;
  if (row0 >= nrows) return;

  const int l15 = lane & 15;
  const int q = lane >> 4;
  const f32x4 zero4 = {0.f, 0.f, 0.f, 0.f};
  const f16x8* B = (const f16x8*)wfrag; // index: (t*4+f)*64 + lane

  // ---- load + split A fragments (4 row-tiles x 2 k-tiles, regs only) ----
  f16x8 xh[MA][2], xl[MA][2];
#pragma unroll
  for (int a = 0; a < MA; ++a)
#pragma unroll
    for (int c = 0; c < 2; ++c) {
      const float* xp = x + (size_t)(row0 + a * 16 + l15) * D + q * 8 + c * 32;
      float v[8];
      *(float4*)&v[0] = *(const float4*)xp;
      *(float4*)&v[4] = *(const float4*)(xp + 4);
      _Float16 hh[8], ll[8];
#pragma unroll
      for (int j = 0; j < 8; ++j) {
        _Float16 h = (_Float16)v[j];
        float r = v[j] - (float)h;
        hh[j] = h;
        ll[j] = (_Float16)(r * 2048.0f);
      }
      xh[a][c] = *(f16x8*)&hh[0];
      xl[a][c] = *(f16x8*)&ll[0];
    }

  float bestm[MA][4];
  int bestt[MA][4];
#pragma unroll
  for (int a = 0; a < MA; ++a)
#pragma unroll
    for (int i = 0; i < 4; ++i) {
      bestm[a][i] = -3.4e38f;
      bestt[a][i] = 0;
    }

  // ---- 25 code tiles, B-frags prefetched one tile ahead ----
  f16x8 bh0 = B[0 * 64 + lane];
  f16x8 bl0 = B[1 * 64 + lane];
  f16x8 bh1 = B[2 * 64 + lane];
  f16x8 bl1 = B[3 * 64 + lane];
  float nn = wnnorm[l15];

  for (int t = 0; t < KT; ++t) {
    int tn = (t + 1 < KT) ? t + 1 : 0;
    f16x8 nbh0 = B[(tn * 4 + 0) * 64 + lane];
    f16x8 nbl0 = B[(tn * 4 + 1) * 64 + lane];
    f16x8 nbh1 = B[(tn * 4 + 2) * 64 + lane];
    f16x8 nbl1 = B[(tn * 4 + 3) * 64 + lane];
    float nnn = wnnorm[tn * 16 + l15];

    f32x4 nrm4 = {nn, nn, nn, nn};
#pragma unroll
    for (int a = 0; a < MA; ++a) {
      f32x4 ah, al;
      ah = __builtin_amdgcn_mfma_f32_16x16x32_f16(xh[a][0], bh0, nrm4, 0, 0, 0);
      ah = __builtin_amdgcn_mfma_f32_16x16x32_f16(xh[a][1], bh1, ah, 0, 0, 0);
      al = __builtin_amdgcn_mfma_f32_16x16x32_f16(xh[a][0], bl0, zero4, 0, 0, 0);
      al = __builtin_amdgcn_mfma_f32_16x16x32_f16(xl[a][0], bh0, al, 0, 0, 0);
      al = __builtin_amdgcn_mfma_f32_16x16x32_f16(xh[a][1], bl1, al, 0, 0, 0);
      al = __builtin_amdgcn_mfma_f32_16x16x32_f16(xl[a][1], bh1, al, 0, 0, 0);
#pragma unroll
      for (int i = 0; i < 4; ++i) {
        float m = fmaf(al[i], 4.8828125e-4f, ah[i]); // (hh-nrm) + 2^-11*cross
        bool gt = m > bestm[a][i];
        bestm[a][i] = gt ? m : bestm[a][i];
        bestt[a][i] = gt ? t : bestt[a][i];
      }
    }
    bh0 = nbh0; bl0 = nbl0; bh1 = nbh1; bl1 = nbl1; nn = nnn;
  }

  // ---- argmin reduce across the 16 lanes of each row-group + write ----
#pragma unroll
  for (int a = 0; a < MA; ++a) {
    float bv[4];
    int bk[4];
#pragma unroll
    for (int i = 0; i < 4; ++i) {
      bv[i] = bestm[a][i];
      bk[i] = bestt[a][i] * 16 + l15;
    }
#pragma unroll
    for (int m = 1; m <= 8; m <<= 1) {
#pragma unroll
      for (int i = 0; i < 4; ++i) {
        float ov = __shfl_xor(bv[i], m, 64);
        int ok = __shfl_xor(bk[i], m, 64);
        bool take = (ov > bv[i]) || ((ov == bv[i]) && (ok < bk[i]));
        bv[i] = take ? ov : bv[i];
        bk[i] = take ? ok : bk[i];
      }
    }
    // lane writes 64B of row (lane>>2); its group (lane>>4) holds that row
    int j = (lane >> 2) & 3;
    int k01 = (j & 1) ? bk[1] : bk[0];
    int k23 = (j & 1) ? bk[3] : bk[2];
    int kk = (j & 2) ? k23 : k01;
    int r = row0 + a * 16 + (lane >> 2);
    const float4* src = (const float4*)(emb + kk * D + (lane & 3) * 16);
    float4* dst = (float4*)(out + (size_t)r * D + (lane & 3) * 16);
#pragma unroll
    for (int s = 0; s < 4; ++s) dst[s] = src[s];
  }
}

// ---- fallback (ws too small): known-correct scalar kernel ----
__global__ __launch_bounds__(256) void vq_naive(const float* __restrict__ x,
                                                const float* __restrict__ emb,
                                                float* __restrict__ out,
                                                int nrows) {
  __shared__ float s_norm[K];
  for (int k = threadIdx.x; k < K; k += blockDim.x) {
    const float* e = emb + k * D;
    float s = 0.f;
#pragma unroll
    for (int d = 0; d < D; ++d) s = fmaf(e[d], e[d], s);
    s_norm[k] = s;
  }
  __syncthreads();
  int r = blockIdx.x * blockDim.x + threadIdx.x;
  if (r >= nrows) return;
  float xr[D];
  const float4* xv = (const float4*)(x + (size_t)r * D);
#pragma unroll
  for (int j = 0; j < D / 4; ++j) {
    float4 t = xv[j];
    xr[4 * j] = t.x; xr[4 * j + 1] = t.y; xr[4 * j + 2] = t.z; xr[4 * j + 3] = t.w;
  }
  float best = 3.4e38f;
  int bestk = 0;
#pragma unroll 2
  for (int k = 0; k < K; ++k) {
    const float* e = emb + k * D;
    float acc = 0.f;
#pragma unroll
    for (int d = 0; d < D; ++d) acc = fmaf(e[d], xr[d], acc);
    float score = fmaf(-2.f, acc, s_norm[k]);
    if (score < best) { best = score; bestk = k; }
  }
  float4* ov = (float4*)(out + (size_t)r * D);
  const float4* ev = (const float4*)(emb + (size_t)bestk * D);
#pragma unroll
  for (int j = 0; j < D / 4; ++j) ov[j] = ev[j];
}

extern "C" void kernel_launch(void* const* d_in, const int* in_sizes, int n_in,
                              void* d_out, int out_size, void* d_ws, size_t ws_size,
                              hipStream_t stream) {
  const float* x = (const float*)d_in[0];
  const float* emb = (const float*)d_in[1];
  float* out = (float*)d_out;
  int nrows = in_sizes[0] / D; // 262144

  if (ws_size < (size_t)WS_NEED) {
    vq_naive<<<(nrows + 255) / 256, 256, 0, stream>>>(x, emb, out, nrows);
    return;
  }

  _Float16* wfrag = (_Float16*)d_ws;
  float* wnnorm = (float*)((char*)d_ws + WS_FRAG_HALVES * 2);

  vq_prep<<<KT, 256, 0, stream>>>(emb, wfrag, wnnorm);
  int nwave = (nrows + 63) / 64;        // 64 rows per wave
  int nblk = (nwave + 3) / 4;           // 4 waves per block
  vq_main<<<nblk, 256, 0, stream>>>(x, wfrag, wnnorm, emb, out, nrows);
}